// Round 17
// baseline (240.113 us; speedup 1.0000x reference)
//
#include <hip/hip_runtime.h>

// Problem: B=4, T=2048, C=512, H=8, D=64.
// Inputs/outputs fp32 (per reference dtypes); internal pipeline bf16.
typedef __bf16 bf16x8 __attribute__((ext_vector_type(8)));
typedef float f32x4 __attribute__((ext_vector_type(4)));
typedef unsigned short ushort8_t __attribute__((ext_vector_type(8)));
typedef unsigned short ushort4_t __attribute__((ext_vector_type(4)));

#define MFMA16(a, b, c) __builtin_amdgcn_mfma_f32_16x16x32_bf16(a, b, c, 0, 0, 0)
#define EXPC 0.18033688011112042f   // log2(e)/8 :  exp(att) = exp2(acc * EXPC)
#define EXP2(x) __builtin_amdgcn_exp2f(x)

__device__ __forceinline__ float bf2f(unsigned short u) {
    union { unsigned int i; float f; } c; c.i = ((unsigned int)u) << 16; return c.f;
}
// native HW convert (RNE)
__device__ __forceinline__ unsigned short f2bf(float f) {
    union { __bf16 h; unsigned short u; } c; c.h = (__bf16)f; return c.u;
}

// ---------------------------------------------------------------- W = qkv + delta (fp32 in -> bf16 W, W^T)
__global__ void prep_w(const float* __restrict__ qkv,
                       const float* __restrict__ delta,
                       unsigned short* __restrict__ W,
                       unsigned short* __restrict__ WT) {
    __shared__ __align__(16) unsigned short tile[64][72];
    const int r0 = blockIdx.x * 64, c0 = blockIdx.y * 64;
    const int rl = threadIdx.x >> 2;
    const int cg = (threadIdx.x & 3) * 16;
    const size_t idx = (size_t)(r0 + rl) * 512 + c0 + cg;
    ushort8_t o0, o1;
    for (int j = 0; j < 8; ++j) {
        o0[j] = f2bf(qkv[idx + j] + delta[idx + j]);
        o1[j] = f2bf(qkv[idx + 8 + j] + delta[idx + 8 + j]);
        tile[rl][cg + j] = o0[j];
        tile[rl][cg + 8 + j] = o1[j];
    }
    *(ushort8_t*)(W + idx) = o0;
    *(ushort8_t*)(W + idx + 8) = o1;
    __syncthreads();
    const int cl = threadIdx.x >> 2;
    const int rg = (threadIdx.x & 3) * 16;
    ushort8_t t0, t1;
    for (int j = 0; j < 8; ++j) {
        t0[j] = tile[rg + j][cl];
        t1[j] = tile[rg + 8 + j][cl];
    }
    const size_t tidx = (size_t)(c0 + cl) * 512 + r0 + rg;
    *(ushort8_t*)(WT + tidx) = t0;
    *(ushort8_t*)(WT + tidx + 8) = t1;
}

// ---------------------------------------------------------------- C[m,n] = sum_k A[m,k]*B[n,k]
// aF32: A fp32 (convert to bf16 during staging); else bf16.
// mode 0: C row-major (M x N) fp32.  mode 1: C scattered into (b,h,t,d) bf16.
__global__ __launch_bounds__(256) void gemm_bt(const void* __restrict__ Ap,
                                               const unsigned short* __restrict__ Bm,
                                               void* __restrict__ Cp,
                                               int M, int N, int K, int mode, int aF32) {
    __shared__ __align__(16) unsigned short As[64][40];
    __shared__ __align__(16) unsigned short Bs[64][40];
    const int tid = threadIdx.x;
    const int wid = tid >> 6, lane = tid & 63;
    const int quad = lane >> 4, l16 = lane & 15;
    const int m0 = blockIdx.x * 64, n0 = blockIdx.y * 64;
    const int waveM = (wid & 1) * 32, waveN = (wid >> 1) * 32;
    const int ldRow = tid >> 2;
    const int ldCol = (tid & 3) * 8;
    f32x4 acc[2][2] = {};
    for (int k0 = 0; k0 < K; k0 += 32) {
        ushort8_t av;
        if (aF32) {
            const float* Af = (const float*)Ap + (size_t)(m0 + ldRow) * K + k0 + ldCol;
            float4 f0 = *(const float4*)(Af);
            float4 f1 = *(const float4*)(Af + 4);
            av[0] = f2bf(f0.x); av[1] = f2bf(f0.y); av[2] = f2bf(f0.z); av[3] = f2bf(f0.w);
            av[4] = f2bf(f1.x); av[5] = f2bf(f1.y); av[6] = f2bf(f1.z); av[7] = f2bf(f1.w);
        } else {
            av = *(const ushort8_t*)((const unsigned short*)Ap + (size_t)(m0 + ldRow) * K + k0 + ldCol);
        }
        ushort8_t bv = *(const ushort8_t*)(Bm + (size_t)(n0 + ldRow) * K + k0 + ldCol);
        __syncthreads();
        *(ushort8_t*)(&As[ldRow][ldCol]) = av;
        *(ushort8_t*)(&Bs[ldRow][ldCol]) = bv;
        __syncthreads();
        bf16x8 a[2], b[2];
        a[0] = *(const bf16x8*)(&As[waveM + l16][quad * 8]);
        a[1] = *(const bf16x8*)(&As[waveM + 16 + l16][quad * 8]);
        b[0] = *(const bf16x8*)(&Bs[waveN + l16][quad * 8]);
        b[1] = *(const bf16x8*)(&Bs[waveN + 16 + l16][quad * 8]);
        for (int mt = 0; mt < 2; ++mt)
            for (int nt = 0; nt < 2; ++nt)
                acc[mt][nt] = MFMA16(a[mt], b[nt], acc[mt][nt]);
    }
    for (int mt = 0; mt < 2; ++mt)
        for (int nt = 0; nt < 2; ++nt)
            for (int r = 0; r < 4; ++r) {
                int gm = m0 + waveM + mt * 16 + quad * 4 + r;   // C/D: row = quad*4+reg
                int gn = n0 + waveN + nt * 16 + l16;            //       col = lane&15
                float v = acc[mt][nt][r];
                if (mode == 0) {
                    ((float*)Cp)[(size_t)gm * N + gn] = v;
                } else {
                    size_t oidx = ((size_t)((gm >> 11) * 8 + (gn >> 6)) * 2048 + (gm & 2047)) * 64 + (gn & 63);
                    ((unsigned short*)Cp)[oidx] = f2bf(v);
                }
            }
}

// ---------------------------------------------------------------- RMSNorm: n1,n2 (bh,t,d) bf16; n3 transposed (bh,d,t) bf16
__global__ void rms_prepare(const unsigned short* __restrict__ w,
                            const float* __restrict__ g1,
                            const float* __restrict__ g2,
                            const float* __restrict__ g3,
                            unsigned short* __restrict__ n1,
                            unsigned short* __restrict__ n2,
                            unsigned short* __restrict__ n3t) {
    __shared__ __align__(16) unsigned short tile[64][72];
    const int bh = blockIdx.y;
    const int t0 = blockIdx.x * 64;
    const int tl = threadIdx.x >> 2;
    const int dg = (threadIdx.x & 3) * 16;
    const size_t rowbase = ((size_t)bh * 2048 + t0 + tl) * 64;
    ushort8_t w0 = *(const ushort8_t*)(w + rowbase + dg);
    ushort8_t w1 = *(const ushort8_t*)(w + rowbase + dg + 8);
    float v[16];
    for (int j = 0; j < 8; ++j) { v[j] = bf2f(w0[j]); v[8 + j] = bf2f(w1[j]); }
    float ss = 0.f;
    for (int j = 0; j < 16; ++j) ss += v[j] * v[j];
    ss += __shfl_xor(ss, 1);
    ss += __shfl_xor(ss, 2);                       // 4 lanes per row share the sum
    const float inv = rsqrtf(ss * (1.0f / 64.0f) + 1.1920929e-07f);
    ushort8_t a0, a1, b0, b1;
    for (int j = 0; j < 16; ++j) {
        int d = dg + j;
        float nb = v[j] * inv;
        unsigned short x1 = f2bf(nb * g1[d]);
        unsigned short x2 = f2bf(nb * g2[d]);
        unsigned short x3 = f2bf(nb * g3[d]);
        if (j < 8) { a0[j] = x1; b0[j] = x2; } else { a1[j - 8] = x1; b1[j - 8] = x2; }
        tile[tl][d] = x3;
    }
    *(ushort8_t*)(n1 + rowbase + dg) = a0;
    *(ushort8_t*)(n1 + rowbase + dg + 8) = a1;
    *(ushort8_t*)(n2 + rowbase + dg) = b0;
    *(ushort8_t*)(n2 + rowbase + dg + 8) = b1;
    __syncthreads();
    const int dr = threadIdx.x >> 2;
    const int tg = (threadIdx.x & 3) * 16;
    ushort8_t o0, o1;
    for (int j = 0; j < 8; ++j) {
        o0[j] = tile[tg + j][dr];
        o1[j] = tile[tg + 8 + j][dr];
    }
    const size_t obase = ((size_t)bh * 64 + dr) * 2048 + t0 + tg;
    *(ushort8_t*)(n3t + obase) = o0;
    *(ushort8_t*)(n3t + obase + 8) = o1;
}

// ---------------------------------------------------------------- E = exp(att): row partial sums + per-block col partials.
// R11: two 64-row K-tiles per phase (128 j per barrier): 8 phases (was 16 barriers),
// 8 INDEPENDENT group-accumulators per phase for ILP (R9 showed occupancy-insensitive,
// so the VGPR rise is safe; the serial group chain was the suspect limiter).
// grid(16,32,2): z covers j-half [z*1024, z*1024+1024).  Row sums PARTIAL ->
// rowPart[z][bh][i] (aliases dead W region); col_reduce merges.
// Staging: linear global load -> chunk^(row&7) swizzled ds_write, same XOR on read.
// att in [-8,8] (unit-RMS rows) -> exp fp32-safe without max subtraction.
__global__ __launch_bounds__(512) void att_sums(const unsigned short* __restrict__ n1,
                                                const unsigned short* __restrict__ n2,
                                                float* __restrict__ rowPart,
                                                float* __restrict__ colPart) {
    __shared__ __align__(16) unsigned short Kbuf[2][128][64];   // 2 phase-buffers x 128 rows
    __shared__ float colAcc[1024];
    const int bh = blockIdx.y;
    const int z = blockIdx.z;
    const int tid = threadIdx.x;
    const int lane = tid & 63, wid = tid >> 6;
    const int quad = lane >> 4, l16 = lane & 15;
    for (int i = tid; i < 1024; i += 512) colAcc[i] = 0.f;
    const int r0 = blockIdx.x * 128 + wid * 16;
    const size_t base = (size_t)bh * 2048 * 64;
    // A-frags (n1 rows of this wave), loaded once: supplies A[m=l16][k=quad*8+e]
    const unsigned short* Ar = n1 + base + (size_t)(r0 + l16) * 64 + quad * 8;
    bf16x8 a0 = *(const bf16x8*)(Ar);
    bf16x8 a1 = *(const bf16x8*)(Ar + 32);
    // staging geometry: thread tid covers (row=tid/8, chunk=tid&7) of EACH of the
    // phase's 2 tiles; global read linear; LDS col = chunk^(row&7) (row+64 same &7).
    const int srow = tid >> 3, schunk = tid & 7;
    const int swslot = (schunk ^ (srow & 7)) * 8;
    const unsigned short* gK = n2 + base + (size_t)(z * 1024 + srow) * 64 + schunk * 8;
    ushort8_t kr0 = *(const ushort8_t*)(gK);
    ushort8_t kr1 = *(const ushort8_t*)(gK + 4096);
    *(ushort8_t*)(&Kbuf[0][srow][swslot]) = kr0;
    *(ushort8_t*)(&Kbuf[0][64 + srow][swslot]) = kr1;
    __syncthreads();
    float rsum[4] = {};
    const int pK0 = (quad ^ (l16 & 7)) * 8;          // swizzled read col for k 0..31
    const int pK1 = ((quad + 4) ^ (l16 & 7)) * 8;    // k 32..63
    int cur = 0;
    for (int p = 0; p < 8; ++p) {
        if (p < 7) {
            kr0 = *(const ushort8_t*)(gK + (size_t)(2 * p + 2) * 4096);   // issue early
            kr1 = *(const ushort8_t*)(gK + (size_t)(2 * p + 3) * 4096);
        }
        for (int g8 = 0; g8 < 8; ++g8) {            // 8 independent acc groups
            const int row = g8 * 16 + l16;          // g8*16 ≡ 0 mod 8 -> same swizzle form
            bf16x8 b0 = *(const bf16x8*)(&Kbuf[cur][row][pK0]);
            bf16x8 b1 = *(const bf16x8*)(&Kbuf[cur][row][pK1]);
            f32x4 acc = {0.f, 0.f, 0.f, 0.f};
            acc = MFMA16(a0, b0, acc);
            acc = MFMA16(a1, b1, acc);
            float ce = 0.f;
            for (int r = 0; r < 4; ++r) {
                float E = EXP2(acc[r] * EXPC);   // E[i=r0+quad*4+r][j=p*128+g8*16+l16]
                rsum[r] += E;
                ce += E;
            }
            ce += __shfl_xor(ce, 16);
            ce += __shfl_xor(ce, 32);            // sum over quads -> col partial over 16 rows
            if (lane < 16) atomicAdd(&colAcc[p * 128 + g8 * 16 + l16], ce);
        }
        if (p < 7) {
            *(ushort8_t*)(&Kbuf[cur ^ 1][srow][swslot]) = kr0;        // write-late
            *(ushort8_t*)(&Kbuf[cur ^ 1][64 + srow][swslot]) = kr1;
        }
        __syncthreads();
        cur ^= 1;
    }
    for (int r = 0; r < 4; ++r) {
        float s = rsum[r];
        s += __shfl_xor(s, 1); s += __shfl_xor(s, 2);
        s += __shfl_xor(s, 4); s += __shfl_xor(s, 8);   // reduce over 16 col-lanes
        if (l16 == 0)
            rowPart[(size_t)z * 65536 + (size_t)bh * 2048 + r0 + quad * 4 + r] = s;
    }
    __syncthreads();
    float4* cp = (float4*)(colPart + ((size_t)bh * 16 + blockIdx.x) * 2048 + z * 1024);
    if (tid < 256) cp[tid] = *(float4*)(&colAcc[tid * 4]);
}

// ---------------------------------------------------------------- colRinv = 1/sum(16 col partials); rowRinv = 1/sum(2 row partials)
__global__ void col_reduce(const float* __restrict__ colPart,
                           const float* __restrict__ rowPart,
                           float* __restrict__ colRinv,
                           float* __restrict__ rowRinv) {
    const int bh = blockIdx.x >> 3;
    const int j = (blockIdx.x & 7) * 256 + threadIdx.x;
    const float* p = colPart + (size_t)bh * 16 * 2048 + j;
    float s = 0.f;
    for (int b = 0; b < 16; ++b) s += p[b * 2048];
    colRinv[(size_t)bh * 2048 + j] = 1.0f / s;
    const size_t ridx = (size_t)bh * 2048 + j;
    rowRinv[ridx] = 1.0f / (rowPart[ridx] + rowPart[65536 + ridx]);
}

// ---------------------------------------------------------------- p = exp(att)*(rinv_row + rinv_col); y^T += n3^T p^T; y -> (b,t,h,d) bf16
// R6 staged structure (measured-good): 8 waves x 16 rows each; block cooperatively
// stages K (n2) and V (n3t) 64-j tiles into double-buffered swizzled LDS; one barrier
// per tile (loads issued before compute, ds_writes after — T14 split).  QK^T swapped
// (acc[r] = att[j=jgrp+quad*4+r][i=r0+l16]) -> packed b64 P write; wave-private pbuf
// round-trip feeds PV.  Each wave owns complete rows -> no cross-wave y merge;
// epilogue is a wave-private LDS transpose aliased over the staging buffers.
__global__ __launch_bounds__(512) void att_apply(const unsigned short* __restrict__ n1,
                                                 const unsigned short* __restrict__ n2,
                                                 const unsigned short* __restrict__ n3t,
                                                 const float* __restrict__ rowRinv,
                                                 const float* __restrict__ colRinv,
                                                 unsigned short* __restrict__ ybuf) {
    __shared__ __align__(16) char smem[51200];
    unsigned short* Kb = (unsigned short*)smem;             // [2][64][64] ushort = 16384B
    unsigned short* Vb = (unsigned short*)(smem + 16384);   // [2][64][64] ushort = 16384B
    unsigned short* pb = (unsigned short*)(smem + 32768);   // [8][16][40] ushort = 10240B
    float* sC = (float*)(smem + 43008);                     // [2048] f32 = 8192B
    const int bh = blockIdx.y;
    const int bb = bh >> 3, hh = bh & 7;
    const int tid = threadIdx.x;
    const int lane = tid & 63, wid = tid >> 6;
    const int quad = lane >> 4, l16 = lane & 15;
    const size_t sbase = (size_t)bh * 2048;
    for (int i = tid; i < 2048; i += 512) sC[i] = colRinv[sbase + i];
    const int r0 = blockIdx.x * 128 + wid * 16;
    const size_t base = sbase * 64;
    const unsigned short* Ar = n1 + base + (size_t)(r0 + l16) * 64 + quad * 8;
    bf16x8 a0 = *(const bf16x8*)(Ar);
    bf16x8 a1 = *(const bf16x8*)(Ar + 32);
    const float rr = rowRinv[sbase + r0 + l16];
    // staging geometry (same swizzle as att_sums)
    const int srow = tid >> 3, schunk = tid & 7;
    const int swslot = (schunk ^ (srow & 7)) * 8;
    const unsigned short* gK = n2 + base + (size_t)srow * 64 + schunk * 8;
    const unsigned short* gV = n3t + (size_t)bh * 64 * 2048 + (size_t)srow * 2048 + schunk * 8;
    ushort8_t kr = *(const ushort8_t*)(gK);
    ushort8_t vr = *(const ushort8_t*)(gV);
    *(ushort8_t*)(Kb + srow * 64 + swslot) = kr;
    *(ushort8_t*)(Vb + srow * 64 + swslot) = vr;
    __syncthreads();
    f32x4 yacc[4] = {};
    const int pK0 = (quad ^ (l16 & 7)) * 8;
    const int pK1 = ((quad + 4) ^ (l16 & 7)) * 8;
    unsigned short* myP = pb + wid * 640 + l16 * 40;
    int cur = 0;
    for (int t = 0; t < 32; ++t) {
        if (t < 31) {
            kr = *(const ushort8_t*)(gK + (size_t)(t + 1) * 4096);   // next K tile (rows)
            vr = *(const ushort8_t*)(gV + (t + 1) * 64);             // next V tile (cols)
        }
        const unsigned short* Kc = Kb + cur * 4096;
        const unsigned short* Vc = Vb + cur * 4096;
        for (int jj = 0; jj < 64; jj += 32) {
            for (int jt = 0; jt < 2; ++jt) {
                const int jgrp = jj + jt * 16;
                bf16x8 b0 = *(const bf16x8*)(Kc + (jgrp + l16) * 64 + pK0);
                bf16x8 b1 = *(const bf16x8*)(Kc + (jgrp + l16) * 64 + pK1);
                const f32x4 cv = *(const f32x4*)(&sC[t * 64 + jgrp + quad * 4]);
                f32x4 acc = {0.f, 0.f, 0.f, 0.f};
                acc = MFMA16(b0, a0, acc);   // swapped: m=j, n=i
                acc = MFMA16(b1, a1, acc);
                ushort4_t pk;
                for (int r = 0; r < 4; ++r) {
                    float E = EXP2(acc[r] * EXPC);
                    pk[r] = f2bf(E * (rr + cv[r]));
                }
                // P[i=l16][jlocal = jt*16+quad*4 .. +3] : one b64 write
                *(ushort4_t*)(myP + jt * 16 + quad * 4) = pk;
            }
            // read P as B-operand: B[n=i=l16][k=jlocal=quad*8+e]
            bf16x8 pf = *(const bf16x8*)(myP + quad * 8);
            const int cbase = jj >> 3;   // chunk base: 0 (jj=0) or 4 (jj=32)
            for (int dt = 0; dt < 4; ++dt) {
                bf16x8 af = *(const bf16x8*)(Vc + (dt * 16 + l16) * 64 +
                                             (((cbase + quad) ^ (l16 & 7)) * 8));
                yacc[dt] = MFMA16(af, pf, yacc[dt]);
            }
        }
        if (t < 31) {
            *(ushort8_t*)(Kb + (cur ^ 1) * 4096 + srow * 64 + swslot) = kr;
            *(ushort8_t*)(Vb + (cur ^ 1) * 4096 + srow * 64 + swslot) = vr;
        }
        __syncthreads();
        cur ^= 1;
    }
    // epilogue: wave-private transpose 64d x 16i (aliased over staging buffers),
    // then coalesced (b,t,h,d) bf16 store.  yacc[dt][r] = y^T[d=dt*16+quad*4+r][i=l16].
    __syncthreads();
    float* myY = (float*)smem + wid * (64 * 17);
    for (int dt = 0; dt < 4; ++dt)
        for (int r = 0; r < 4; ++r)
            myY[(dt * 16 + quad * 4 + r) * 17 + l16] = yacc[dt][r];
    for (int it = 0; it < 2; ++it) {
        int row = it * 8 + (lane >> 3);
        int dgp = (lane & 7) * 8;
        ushort8_t pk;
        for (int j = 0; j < 8; ++j) pk[j] = f2bf(myY[(dgp + j) * 17 + row]);
        int tg = r0 + row;
        size_t oidx = ((size_t)(bb * 2048 + tg) * 512) + hh * 64 + dgp;
        *(ushort8_t*)(ybuf + oidx) = pk;
    }
}

extern "C" void kernel_launch(void* const* d_in, const int* in_sizes, int n_in,
                              void* d_out, int out_size, void* d_ws, size_t ws_size,
                              hipStream_t stream) {
    const float* x   = (const float*)d_in[0];
    const float* dlt = (const float*)d_in[1];
    const float* qkv = (const float*)d_in[2];
    const float* g1  = (const float*)d_in[3];
    const float* g2  = (const float*)d_in[4];
    const float* g3  = (const float*)d_in[5];
    float* out = (float*)d_out;
    char* ws = (char*)d_ws;
    // workspace layout (33.5 MiB). Region reuse:
    //  +0        W (512KB, dead after gemm#1)  -> rowPart[2][32][2048] f32 (512KB exactly)
    //  +1MB      wb (dead after rms_prepare) -> colPart (8MB, dead after col_reduce) -> yb
    unsigned short* W   = (unsigned short*)(ws);
    float*          rowPart = (float*)(ws);
    unsigned short* WT  = (unsigned short*)(ws + 524288);
    unsigned short* wb  = (unsigned short*)(ws + 1048576);
    float*          colPart = (float*)(ws + 1048576);
    unsigned short* yb  = wb;
    unsigned short* n1  = (unsigned short*)(ws + 9437184);
    unsigned short* n2  = (unsigned short*)(ws + 17825792);
    unsigned short* n3t = (unsigned short*)(ws + 26214400);
    float* rowRinv = (float*)(ws + 34603008);
    float* colRinv = (float*)(ws + 34865152);

    prep_w<<<dim3(8, 8), 256, 0, stream>>>(qkv, dlt, W, WT);
    gemm_bt<<<dim3(128, 8), 256, 0, stream>>>(x, W, wb, 8192, 512, 512, 1, 1);
    rms_prepare<<<dim3(32, 32), 256, 0, stream>>>(wb, g1, g2, g3, n1, n2, n3t);
    att_sums<<<dim3(16, 32, 2), 512, 0, stream>>>(n1, n2, rowPart, colPart);
    col_reduce<<<256, 256, 0, stream>>>(colPart, rowPart, colRinv, rowRinv);
    att_apply<<<dim3(16, 32), 512, 0, stream>>>(n1, n2, n3t, rowRinv, colRinv, yb);
    gemm_bt<<<dim3(128, 8), 256, 0, stream>>>(yb, WT, out, 8192, 512, 512, 0, 0);
}

// Round 19
// 206.772 us; speedup vs baseline: 1.1612x; 1.1612x over previous
//
#include <hip/hip_runtime.h>

// Problem: B=4, T=2048, C=512, H=8, D=64.
// Inputs/outputs fp32 (per reference dtypes); internal pipeline bf16.
typedef __bf16 bf16x8 __attribute__((ext_vector_type(8)));
typedef float f32x4 __attribute__((ext_vector_type(4)));
typedef unsigned short ushort8_t __attribute__((ext_vector_type(8)));
typedef unsigned short ushort4_t __attribute__((ext_vector_type(4)));

#define MFMA16(a, b, c) __builtin_amdgcn_mfma_f32_16x16x32_bf16(a, b, c, 0, 0, 0)
#define EXPC 0.18033688011112042f   // log2(e)/8 :  exp(att) = exp2(acc * EXPC)
#define EXP2(x) __builtin_amdgcn_exp2f(x)

__device__ __forceinline__ float bf2f(unsigned short u) {
    union { unsigned int i; float f; } c; c.i = ((unsigned int)u) << 16; return c.f;
}
// native HW convert (RNE)
__device__ __forceinline__ unsigned short f2bf(float f) {
    union { __bf16 h; unsigned short u; } c; c.h = (__bf16)f; return c.u;
}

// ---------------------------------------------------------------- W = qkv + delta (fp32 in -> bf16 W, W^T); also zero the sums accumulator
__global__ void prep_w(const float* __restrict__ qkv,
                       const float* __restrict__ delta,
                       unsigned short* __restrict__ W,
                       unsigned short* __restrict__ WT,
                       float* __restrict__ sums) {
    __shared__ __align__(16) unsigned short tile[64][72];
    const int r0 = blockIdx.x * 64, c0 = blockIdx.y * 64;
    // zero sums[32][2048] (65536 floats): 64 blocks x 256 threads x 1 float4
    {
        const int lin = (blockIdx.y * 8 + blockIdx.x) * 256 + threadIdx.x;
        float4 z = {0.f, 0.f, 0.f, 0.f};
        *(float4*)(sums + (size_t)lin * 4) = z;
    }
    const int rl = threadIdx.x >> 2;
    const int cg = (threadIdx.x & 3) * 16;
    const size_t idx = (size_t)(r0 + rl) * 512 + c0 + cg;
    ushort8_t o0, o1;
    for (int j = 0; j < 8; ++j) {
        o0[j] = f2bf(qkv[idx + j] + delta[idx + j]);
        o1[j] = f2bf(qkv[idx + 8 + j] + delta[idx + 8 + j]);
        tile[rl][cg + j] = o0[j];
        tile[rl][cg + 8 + j] = o1[j];
    }
    *(ushort8_t*)(W + idx) = o0;
    *(ushort8_t*)(W + idx + 8) = o1;
    __syncthreads();
    const int cl = threadIdx.x >> 2;
    const int rg = (threadIdx.x & 3) * 16;
    ushort8_t t0, t1;
    for (int j = 0; j < 8; ++j) {
        t0[j] = tile[rg + j][cl];
        t1[j] = tile[rg + 8 + j][cl];
    }
    const size_t tidx = (size_t)(c0 + cl) * 512 + r0 + rg;
    *(ushort8_t*)(WT + tidx) = t0;
    *(ushort8_t*)(WT + tidx + 8) = t1;
}

// ---------------------------------------------------------------- C[m,n] = sum_k A[m,k]*B[n,k]
// aF32: A fp32 (convert to bf16 during staging); else bf16.
// mode 0: C row-major (M x N) fp32.  mode 1: C scattered into (b,h,t,d) bf16.
__global__ __launch_bounds__(256) void gemm_bt(const void* __restrict__ Ap,
                                               const unsigned short* __restrict__ Bm,
                                               void* __restrict__ Cp,
                                               int M, int N, int K, int mode, int aF32) {
    __shared__ __align__(16) unsigned short As[64][40];
    __shared__ __align__(16) unsigned short Bs[64][40];
    const int tid = threadIdx.x;
    const int wid = tid >> 6, lane = tid & 63;
    const int quad = lane >> 4, l16 = lane & 15;
    const int m0 = blockIdx.x * 64, n0 = blockIdx.y * 64;
    const int waveM = (wid & 1) * 32, waveN = (wid >> 1) * 32;
    const int ldRow = tid >> 2;
    const int ldCol = (tid & 3) * 8;
    f32x4 acc[2][2] = {};
    for (int k0 = 0; k0 < K; k0 += 32) {
        ushort8_t av;
        if (aF32) {
            const float* Af = (const float*)Ap + (size_t)(m0 + ldRow) * K + k0 + ldCol;
            float4 f0 = *(const float4*)(Af);
            float4 f1 = *(const float4*)(Af + 4);
            av[0] = f2bf(f0.x); av[1] = f2bf(f0.y); av[2] = f2bf(f0.z); av[3] = f2bf(f0.w);
            av[4] = f2bf(f1.x); av[5] = f2bf(f1.y); av[6] = f2bf(f1.z); av[7] = f2bf(f1.w);
        } else {
            av = *(const ushort8_t*)((const unsigned short*)Ap + (size_t)(m0 + ldRow) * K + k0 + ldCol);
        }
        ushort8_t bv = *(const ushort8_t*)(Bm + (size_t)(n0 + ldRow) * K + k0 + ldCol);
        __syncthreads();
        *(ushort8_t*)(&As[ldRow][ldCol]) = av;
        *(ushort8_t*)(&Bs[ldRow][ldCol]) = bv;
        __syncthreads();
        bf16x8 a[2], b[2];
        a[0] = *(const bf16x8*)(&As[waveM + l16][quad * 8]);
        a[1] = *(const bf16x8*)(&As[waveM + 16 + l16][quad * 8]);
        b[0] = *(const bf16x8*)(&Bs[waveN + l16][quad * 8]);
        b[1] = *(const bf16x8*)(&Bs[waveN + 16 + l16][quad * 8]);
        for (int mt = 0; mt < 2; ++mt)
            for (int nt = 0; nt < 2; ++nt)
                acc[mt][nt] = MFMA16(a[mt], b[nt], acc[mt][nt]);
    }
    for (int mt = 0; mt < 2; ++mt)
        for (int nt = 0; nt < 2; ++nt)
            for (int r = 0; r < 4; ++r) {
                int gm = m0 + waveM + mt * 16 + quad * 4 + r;   // C/D: row = quad*4+reg
                int gn = n0 + waveN + nt * 16 + l16;            //       col = lane&15
                float v = acc[mt][nt][r];
                if (mode == 0) {
                    ((float*)Cp)[(size_t)gm * N + gn] = v;
                } else {
                    size_t oidx = ((size_t)((gm >> 11) * 8 + (gn >> 6)) * 2048 + (gm & 2047)) * 64 + (gn & 63);
                    ((unsigned short*)Cp)[oidx] = f2bf(v);
                }
            }
}

// ---------------------------------------------------------------- RMSNorm: n1,n2 (bh,t,d) bf16; n3 transposed (bh,d,t) bf16
__global__ void rms_prepare(const unsigned short* __restrict__ w,
                            const float* __restrict__ g1,
                            const float* __restrict__ g2,
                            const float* __restrict__ g3,
                            unsigned short* __restrict__ n1,
                            unsigned short* __restrict__ n2,
                            unsigned short* __restrict__ n3t) {
    __shared__ __align__(16) unsigned short tile[64][72];
    const int bh = blockIdx.y;
    const int t0 = blockIdx.x * 64;
    const int tl = threadIdx.x >> 2;
    const int dg = (threadIdx.x & 3) * 16;
    const size_t rowbase = ((size_t)bh * 2048 + t0 + tl) * 64;
    ushort8_t w0 = *(const ushort8_t*)(w + rowbase + dg);
    ushort8_t w1 = *(const ushort8_t*)(w + rowbase + dg + 8);
    float v[16];
    for (int j = 0; j < 8; ++j) { v[j] = bf2f(w0[j]); v[8 + j] = bf2f(w1[j]); }
    float ss = 0.f;
    for (int j = 0; j < 16; ++j) ss += v[j] * v[j];
    ss += __shfl_xor(ss, 1);
    ss += __shfl_xor(ss, 2);                       // 4 lanes per row share the sum
    const float inv = rsqrtf(ss * (1.0f / 64.0f) + 1.1920929e-07f);
    ushort8_t a0, a1, b0, b1;
    for (int j = 0; j < 16; ++j) {
        int d = dg + j;
        float nb = v[j] * inv;
        unsigned short x1 = f2bf(nb * g1[d]);
        unsigned short x2 = f2bf(nb * g2[d]);
        unsigned short x3 = f2bf(nb * g3[d]);
        if (j < 8) { a0[j] = x1; b0[j] = x2; } else { a1[j - 8] = x1; b1[j - 8] = x2; }
        tile[tl][d] = x3;
    }
    *(ushort8_t*)(n1 + rowbase + dg) = a0;
    *(ushort8_t*)(n1 + rowbase + dg + 8) = a1;
    *(ushort8_t*)(n2 + rowbase + dg) = b0;
    *(ushort8_t*)(n2 + rowbase + dg + 8) = b1;
    __syncthreads();
    const int dr = threadIdx.x >> 2;
    const int tg = (threadIdx.x & 3) * 16;
    ushort8_t o0, o1;
    for (int j = 0; j < 8; ++j) {
        o0[j] = tile[tg + j][dr];
        o1[j] = tile[tg + 8 + j][dr];
    }
    const size_t obase = ((size_t)bh * 64 + dr) * 2048 + t0 + tg;
    *(ushort8_t*)(n3t + obase) = o0;
    *(ushort8_t*)(n3t + obase + 8) = o1;
}

// ---------------------------------------------------------------- s = row sums of exp(att) (== col sums: att is SYMMETRIC).
// att_ij = inv_i*inv_j*sum_d(w_i w_j g1 g2) = att_ji  ->  colsum == rowsum == s.
// Upper-triangle tiling: 136 super-tile pairs (bi<=bj) of 128 rows, grid (136, 32).
// Off-diagonal tile (bi<bj): E computed once; its ROW sums feed s[bi-rows], its COL
// sums feed s[bj-rows] (symmetry: lower-triangle row contributions).  Diagonal tile:
// full 128x128, row sums only.  Element-work = 53% of the full sweep.
// Accumulation via global atomicAdd into pre-zeroed sums[32][2048].
// att in [-8,8] (unit-RMS rows) -> exp fp32-safe without max subtraction.
__global__ __launch_bounds__(512) void att_sums_tri(const unsigned short* __restrict__ n1,
                                                    const unsigned short* __restrict__ n2,
                                                    float* __restrict__ sums) {
    __shared__ __align__(16) unsigned short Kbuf[128][64];   // chunk-swizzled rows (16 KB)
    __shared__ float colAcc[128];
    const int bh = blockIdx.y;
    const int tid = threadIdx.x;
    const int lane = tid & 63, wid = tid >> 6;
    const int quad = lane >> 4, l16 = lane & 15;
    // decode upper-triangle pair (bi <= bj) from blockIdx.x in [0,136)
    int rem = blockIdx.x, bi = 0;
    while (rem >= 16 - bi) { rem -= 16 - bi; ++bi; }
    const int bj = bi + rem;
    const int diag = (bi == bj);
    if (tid < 128) colAcc[tid] = 0.f;
    const size_t base = (size_t)bh * 2048 * 64;
    // A-frags: wave's 16 rows of tile bi
    const int r0 = bi * 128 + wid * 16;
    const unsigned short* Ar = n1 + base + (size_t)(r0 + l16) * 64 + quad * 8;
    bf16x8 a0 = *(const bf16x8*)(Ar);
    bf16x8 a1 = *(const bf16x8*)(Ar + 32);
    // stage K: 128 rows of tile bj (n2), linear global -> chunk^(row&7) swizzled LDS
    const int srow = tid >> 3, schunk = tid & 7;
    const int swslot = (schunk ^ (srow & 7)) * 8;
    const unsigned short* gK = n2 + base + (size_t)(bj * 128 + srow) * 64 + schunk * 8;
    ushort8_t k0 = *(const ushort8_t*)(gK);
    ushort8_t k1 = *(const ushort8_t*)(gK + 64 * 64);
    *(ushort8_t*)(&Kbuf[srow][swslot]) = k0;
    *(ushort8_t*)(&Kbuf[64 + srow][swslot]) = k1;   // (srow+64)&7 == srow&7
    __syncthreads();
    float rsum[4] = {};
    const int pK0 = (quad ^ (l16 & 7)) * 8;          // swizzled read col for k 0..31
    const int pK1 = ((quad + 4) ^ (l16 & 7)) * 8;    // k 32..63
    for (int g8 = 0; g8 < 8; ++g8) {                 // 8 j-groups of 16 (128 tile cols)
        const int row = g8 * 16 + l16;               // g8*16 ≡ 0 mod 8 -> same swizzle form
        bf16x8 b0 = *(const bf16x8*)(&Kbuf[row][pK0]);
        bf16x8 b1 = *(const bf16x8*)(&Kbuf[row][pK1]);
        f32x4 acc = {0.f, 0.f, 0.f, 0.f};
        acc = MFMA16(a0, b0, acc);
        acc = MFMA16(a1, b1, acc);
        float ce = 0.f;
        for (int r = 0; r < 4; ++r) {
            float E = EXP2(acc[r] * EXPC);   // E[i=r0+quad*4+r][jloc=g8*16+l16]
            rsum[r] += E;
            ce += E;
        }
        ce += __shfl_xor(ce, 16);
        ce += __shfl_xor(ce, 32);            // sum over quads -> col partial over 16 rows
        if (lane < 16) atomicAdd(&colAcc[g8 * 16 + l16], ce);
    }
    // row sums -> s[bi rows]
    for (int r = 0; r < 4; ++r) {
        float s = rsum[r];
        s += __shfl_xor(s, 1); s += __shfl_xor(s, 2);
        s += __shfl_xor(s, 4); s += __shfl_xor(s, 8);   // reduce over 16 col-lanes
        if (l16 == 0)
            atomicAdd(&sums[(size_t)bh * 2048 + r0 + quad * 4 + r], s);
    }
    // col sums (= transposed-row contributions) -> s[bj rows]; skip on diagonal
    __syncthreads();
    if (!diag && tid < 128)
        atomicAdd(&sums[(size_t)bh * 2048 + bj * 128 + tid], colAcc[tid]);
}

// ---------------------------------------------------------------- sRinv = 1/sums
__global__ void recip(const float* __restrict__ sums, float* __restrict__ sRinv) {
    const int i = blockIdx.x * 256 + threadIdx.x;
    sRinv[i] = 1.0f / sums[i];
}

// ---------------------------------------------------------------- p = exp(att)*(rinv_row + rinv_col); y^T += n3^T p^T; y -> (b,t,h,d) bf16
// R6 staged structure (measured-good): 8 waves x 16 rows each; block cooperatively
// stages K (n2) and V (n3t) 64-j tiles into double-buffered swizzled LDS; one barrier
// per tile (loads issued before compute, ds_writes after — T14 split).  QK^T swapped
// (acc[r] = att[j=jgrp+quad*4+r][i=r0+l16]) -> packed b64 P write; wave-private pbuf
// round-trip feeds PV.  Each wave owns complete rows -> no cross-wave y merge;
// epilogue is a wave-private LDS transpose aliased over the staging buffers.
// By symmetry rowRinv == colRinv == sRinv (same buffer passed twice).
__global__ __launch_bounds__(512) void att_apply(const unsigned short* __restrict__ n1,
                                                 const unsigned short* __restrict__ n2,
                                                 const unsigned short* __restrict__ n3t,
                                                 const float* __restrict__ rowRinv,
                                                 const float* __restrict__ colRinv,
                                                 unsigned short* __restrict__ ybuf) {
    __shared__ __align__(16) char smem[51200];
    unsigned short* Kb = (unsigned short*)smem;             // [2][64][64] ushort = 16384B
    unsigned short* Vb = (unsigned short*)(smem + 16384);   // [2][64][64] ushort = 16384B
    unsigned short* pb = (unsigned short*)(smem + 32768);   // [8][16][40] ushort = 10240B
    float* sC = (float*)(smem + 43008);                     // [2048] f32 = 8192B
    const int bh = blockIdx.y;
    const int bb = bh >> 3, hh = bh & 7;
    const int tid = threadIdx.x;
    const int lane = tid & 63, wid = tid >> 6;
    const int quad = lane >> 4, l16 = lane & 15;
    const size_t sbase = (size_t)bh * 2048;
    for (int i = tid; i < 2048; i += 512) sC[i] = colRinv[sbase + i];
    const int r0 = blockIdx.x * 128 + wid * 16;
    const size_t base = sbase * 64;
    const unsigned short* Ar = n1 + base + (size_t)(r0 + l16) * 64 + quad * 8;
    bf16x8 a0 = *(const bf16x8*)(Ar);
    bf16x8 a1 = *(const bf16x8*)(Ar + 32);
    const float rr = rowRinv[sbase + r0 + l16];
    // staging geometry (same swizzle as att_sums)
    const int srow = tid >> 3, schunk = tid & 7;
    const int swslot = (schunk ^ (srow & 7)) * 8;
    const unsigned short* gK = n2 + base + (size_t)srow * 64 + schunk * 8;
    const unsigned short* gV = n3t + (size_t)bh * 64 * 2048 + (size_t)srow * 2048 + schunk * 8;
    ushort8_t kr = *(const ushort8_t*)(gK);
    ushort8_t vr = *(const ushort8_t*)(gV);
    *(ushort8_t*)(Kb + srow * 64 + swslot) = kr;
    *(ushort8_t*)(Vb + srow * 64 + swslot) = vr;
    __syncthreads();
    f32x4 yacc[4] = {};
    const int pK0 = (quad ^ (l16 & 7)) * 8;
    const int pK1 = ((quad + 4) ^ (l16 & 7)) * 8;
    unsigned short* myP = pb + wid * 640 + l16 * 40;
    int cur = 0;
    for (int t = 0; t < 32; ++t) {
        if (t < 31) {
            kr = *(const ushort8_t*)(gK + (size_t)(t + 1) * 4096);   // next K tile (rows)
            vr = *(const ushort8_t*)(gV + (t + 1) * 64);             // next V tile (cols)
        }
        const unsigned short* Kc = Kb + cur * 4096;
        const unsigned short* Vc = Vb + cur * 4096;
        for (int jj = 0; jj < 64; jj += 32) {
            for (int jt = 0; jt < 2; ++jt) {
                const int jgrp = jj + jt * 16;
                bf16x8 b0 = *(const bf16x8*)(Kc + (jgrp + l16) * 64 + pK0);
                bf16x8 b1 = *(const bf16x8*)(Kc + (jgrp + l16) * 64 + pK1);
                const f32x4 cv = *(const f32x4*)(&sC[t * 64 + jgrp + quad * 4]);
                f32x4 acc = {0.f, 0.f, 0.f, 0.f};
                acc = MFMA16(b0, a0, acc);   // swapped: m=j, n=i
                acc = MFMA16(b1, a1, acc);
                ushort4_t pk;
                for (int r = 0; r < 4; ++r) {
                    float E = EXP2(acc[r] * EXPC);
                    pk[r] = f2bf(E * (rr + cv[r]));
                }
                // P[i=l16][jlocal = jt*16+quad*4 .. +3] : one b64 write
                *(ushort4_t*)(myP + jt * 16 + quad * 4) = pk;
            }
            // read P as B-operand: B[n=i=l16][k=jlocal=quad*8+e]
            bf16x8 pf = *(const bf16x8*)(myP + quad * 8);
            const int cbase = jj >> 3;   // chunk base: 0 (jj=0) or 4 (jj=32)
            for (int dt = 0; dt < 4; ++dt) {
                bf16x8 af = *(const bf16x8*)(Vc + (dt * 16 + l16) * 64 +
                                             (((cbase + quad) ^ (l16 & 7)) * 8));
                yacc[dt] = MFMA16(af, pf, yacc[dt]);
            }
        }
        if (t < 31) {
            *(ushort8_t*)(Kb + (cur ^ 1) * 4096 + srow * 64 + swslot) = kr;
            *(ushort8_t*)(Vb + (cur ^ 1) * 4096 + srow * 64 + swslot) = vr;
        }
        __syncthreads();
        cur ^= 1;
    }
    // epilogue: wave-private transpose 64d x 16i (aliased over staging buffers),
    // then coalesced (b,t,h,d) bf16 store.  yacc[dt][r] = y^T[d=dt*16+quad*4+r][i=l16].
    __syncthreads();
    float* myY = (float*)smem + wid * (64 * 17);
    for (int dt = 0; dt < 4; ++dt)
        for (int r = 0; r < 4; ++r)
            myY[(dt * 16 + quad * 4 + r) * 17 + l16] = yacc[dt][r];
    for (int it = 0; it < 2; ++it) {
        int row = it * 8 + (lane >> 3);
        int dgp = (lane & 7) * 8;
        ushort8_t pk;
        for (int j = 0; j < 8; ++j) pk[j] = f2bf(myY[(dgp + j) * 17 + row]);
        int tg = r0 + row;
        size_t oidx = ((size_t)(bb * 2048 + tg) * 512) + hh * 64 + dgp;
        *(ushort8_t*)(ybuf + oidx) = pk;
    }
}

extern "C" void kernel_launch(void* const* d_in, const int* in_sizes, int n_in,
                              void* d_out, int out_size, void* d_ws, size_t ws_size,
                              hipStream_t stream) {
    const float* x   = (const float*)d_in[0];
    const float* dlt = (const float*)d_in[1];
    const float* qkv = (const float*)d_in[2];
    const float* g1  = (const float*)d_in[3];
    const float* g2  = (const float*)d_in[4];
    const float* g3  = (const float*)d_in[5];
    float* out = (float*)d_out;
    char* ws = (char*)d_ws;
    // workspace layout (33.5 MiB):
    //  +0      W (512KB, dead after gemm#1); +512KB WT
    //  +1MB    wb (dead after rms_prepare) -> yb
    //  +34603008  sums[32][2048] f32 (256KB, zeroed by prep_w)
    //  +34865152  sRinv[32][2048] f32 (256KB)
    unsigned short* W   = (unsigned short*)(ws);
    unsigned short* WT  = (unsigned short*)(ws + 524288);
    unsigned short* wb  = (unsigned short*)(ws + 1048576);
    unsigned short* yb  = wb;
    unsigned short* n1  = (unsigned short*)(ws + 9437184);
    unsigned short* n2  = (unsigned short*)(ws + 17825792);
    unsigned short* n3t = (unsigned short*)(ws + 26214400);
    float* sums  = (float*)(ws + 34603008);
    float* sRinv = (float*)(ws + 34865152);

    prep_w<<<dim3(8, 8), 256, 0, stream>>>(qkv, dlt, W, WT, sums);
    gemm_bt<<<dim3(128, 8), 256, 0, stream>>>(x, W, wb, 8192, 512, 512, 1, 1);
    rms_prepare<<<dim3(32, 32), 256, 0, stream>>>(wb, g1, g2, g3, n1, n2, n3t);
    att_sums_tri<<<dim3(136, 32), 512, 0, stream>>>(n1, n2, sums);
    recip<<<256, 256, 0, stream>>>(sums, sRinv);
    att_apply<<<dim3(16, 32), 512, 0, stream>>>(n1, n2, n3t, sRinv, sRinv, yb);
    gemm_bt<<<dim3(128, 8), 256, 0, stream>>>(yb, WT, out, 8192, 512, 512, 0, 0);
}